// Round 14
// baseline (2256.899 us; speedup 1.0000x reference)
//
#include <hip/hip_runtime.h>
#include <math.h>

#define NXY 513
#define NIN 511
#define NL3 3
#define NE4 4
#define NB 12
#define GLD 512

static constexpr long FS  = (long)NE4 * NL3 * NXY * NXY;   // 3,158,028 floats
static constexpr long GSZ = (long)NB * GLD * GLD;          // 3,145,728 elements
static constexpr int  NSTEPS = 4;

static constexpr double dF0 = 9.375e-05;
static constexpr double dDX = 10000.0;
static constexpr float ZFBCf     = (float)(0.2 / (1.0 + 0.5 * 0.2));
static constexpr float JACCf     = (float)(1.0 / (dF0 * dDX * dDX));
static constexpr float HYPCf     = (float)(2.0e9 / (dF0 * dF0) / (dDX*dDX*dDX*dDX*dDX*dDX));
static constexpr float BFCf      = (float)(2.0 / (2.0 * dF0 * dDX * dDX * (-2900.0)));
static constexpr float INVF0DX2f = (float)(1.0 / ((dF0 * dDX) * (dF0 * dDX)));

typedef short  bf16x8 __attribute__((ext_vector_type(8)));
typedef float  f32x4  __attribute__((ext_vector_type(4)));
typedef unsigned int u32;
typedef __attribute__((address_space(1))) const u32 GAS;
typedef __attribute__((address_space(3))) u32 LAS;
#define GLDS(gp, lp) __builtin_amdgcn_global_load_lds((GAS*)(gp), (LAS*)(lp), 16, 0, 0)

__device__ __forceinline__ unsigned short f2bf(float x) {
    unsigned int u = __float_as_uint(x);
    return (unsigned short)((u + 0x7FFFu + ((u >> 16) & 1u)) >> 16);
}
__device__ __forceinline__ float bf2f(unsigned short h) {
    return __uint_as_float(((unsigned int)h) << 16);
}

// ---------------- parity-split DST matrices (bf16 hi/lo), 256x256 each --------------------------
__global__ void initB_kernel(unsigned short* __restrict__ BoH, unsigned short* __restrict__ BoL,
                             unsigned short* __restrict__ BeH, unsigned short* __restrict__ BeL) {
    int j = threadIdx.x;
    int n = blockIdx.x;
    int idx = n * 256 + j;
    int mo = ((n + 1) * (2 * j + 1)) & 1023;
    int me = ((n + 1) * (2 * j + 2)) & 1023;
    float fo = (float)(0.0625 * sin(M_PI * (double)mo / 512.0));
    float fe = (float)(0.0625 * sin(M_PI * (double)me / 512.0));
    unsigned short oh = f2bf(fo);
    BoH[idx] = oh; BoL[idx] = f2bf(fo - bf2f(oh));
    unsigned short eh = f2bf(fe);
    BeH[idx] = eh; BeL[idx] = f2bf(fe - bf2f(eh));
}

// ---------------- fused lap(lap_bc(lap_bc(p))) + jacobian + wind + friction (12 planes) ---------
__global__ __launch_bounds__(256) void fused_rhs(
    float* __restrict__ kq, const float* __restrict__ q, const float* __restrict__ p,
    const float* __restrict__ wind)
{
    __shared__ float ps[22][72];
    __shared__ float qs[22][72];
    __shared__ float l1[22][72];
    __shared__ float l2[22][72];
    const int c  = blockIdx.z;
    const int x0 = 1 + blockIdx.y * 16;
    const int y0 = 1 + blockIdx.x * 64;
    const int t  = threadIdx.x;
    const size_t off = (size_t)c * NXY * NXY;
    const float* pp = p + off;
    const float* qp = q + off;

    for (int idx = t; idx < 22 * 70; idx += 256) {
        int i = idx / 70, j = idx % 70;
        int gx = x0 - 3 + i, gy = y0 - 3 + j;
        bool in = (gx >= 0 && gx < NXY && gy >= 0 && gy < NXY);
        size_t go = (size_t)gx * NXY + gy;
        ps[i][j] = in ? pp[go] : 0.f;
        qs[i][j] = in ? qp[go] : 0.f;
    }
    __syncthreads();

#define LAPBC(a, i, j, gx, gy) \
    ((gy) == 0       ? ZFBCf * (a[i][(j)+1] - a[i][j]) : \
     (gy) == NXY-1   ? ZFBCf * (a[i][(j)-1] - a[i][j]) : \
     (gx) == 0       ? ZFBCf * (a[(i)+1][j] - a[i][j]) : \
     (gx) == NXY-1   ? ZFBCf * (a[(i)-1][j] - a[i][j]) : \
     a[(i)+1][j] + a[(i)-1][j] + a[i][(j)+1] + a[i][(j)-1] - 4.f * a[i][j])

    for (int idx = t; idx < 20 * 68; idx += 256) {
        int i = 1 + idx / 68, j = 1 + idx % 68;
        int gx = x0 - 3 + i, gy = y0 - 3 + j;
        float v = 0.f;
        if (gx >= 0 && gx < NXY && gy >= 0 && gy < NXY) v = LAPBC(ps, i, j, gx, gy);
        l1[i][j] = v;
    }
    __syncthreads();

    for (int idx = t; idx < 18 * 66; idx += 256) {
        int i = 2 + idx / 66, j = 2 + idx % 66;
        int gx = x0 - 3 + i, gy = y0 - 3 + j;
        float v = 0.f;
        if (gx >= 0 && gx < NXY && gy >= 0 && gy < NXY) v = LAPBC(l1, i, j, gx, gy);
        l2[i][j] = v;
    }
    __syncthreads();
#undef LAPBC

    const int l = c % NL3;
    for (int idx = t; idx < 16 * 64; idx += 256) {
        int i = 3 + idx / 64, j = 3 + idx % 64;
        int gx = x0 - 3 + i, gy = y0 - 3 + j;
        if (gx > NIN || gy > NIN) continue;
        float fmm=qs[i-1][j-1], fm0=qs[i-1][j], fmp=qs[i-1][j+1];
        float f0m=qs[i][j-1],                    f0p=qs[i][j+1];
        float fpm=qs[i+1][j-1], fp0=qs[i+1][j], fpp=qs[i+1][j+1];
        float gmm=ps[i-1][j-1], gm0=ps[i-1][j], gmp=ps[i-1][j+1];
        float g0m=ps[i][j-1],   g00=ps[i][j],   g0p=ps[i][j+1];
        float gpm=ps[i+1][j-1], gp0=ps[i+1][j], gpp=ps[i+1][j+1];
        float J1 = (fp0 - fm0) * (g0p - g0m) - (gp0 - gm0) * (f0p - f0m);
        float J2 = fp0 * (gpp - gpm) - fm0 * (gmp - gmm);
        float J3 = f0p * (gpp - gmp) - f0m * (gpm - gmm);
        float J4 = g0p * (fpp - fmp) - g0m * (fpm - fmm);
        float J5 = gp0 * (fpp - fpm) - gm0 * (fmp - fmm);
        float jac = (J1 + J2 - J3 + J4 - J5) * (1.0f / 12.0f);
        float lap3 = l2[i+1][j] + l2[i-1][j] + l2[i][j+1] + l2[i][j-1] - 4.f * l2[i][j];
        float v = JACCf * jac - HYPCf * lap3;
        if (l == 0)       v += wind[(size_t)(gx-1) * NIN + (gy-1)];
        if (l == NL3-1)   v += BFCf * (gp0 + gm0 + g0p + g0m - 4.f * g00);
        kq[off + (size_t)gx * NXY + gy] = v;
    }
}

// ---------------- layer->mode, writes bf16 hi/lo in PARITY-SPLIT layout ------------------------
__global__ void l2m_kernel(unsigned short* __restrict__ Gh, unsigned short* __restrict__ Gl,
                           const float* __restrict__ kq, const float* __restrict__ Cl2m) {
    int p  = blockIdx.x * blockDim.x + threadIdx.x;   // pair index 0..255
    int rx = blockIdx.y * blockDim.y + threadIdx.y;   // 0..511
    int e = blockIdx.z;
    int ry0 = 2 * p, ry1 = 2 * p + 1;
    float vA[3] = {0.f, 0.f, 0.f}, vB[3] = {0.f, 0.f, 0.f};
    if (rx < NIN) {
        size_t base = ((size_t)(e * NL3) * NXY + (rx + 1)) * NXY;
        if (ry0 < NIN) {
            float f0 = kq[base + ry0 + 1];
            float f1 = kq[base + (size_t)NXY*NXY + ry0 + 1];
            float f2 = kq[base + 2*(size_t)NXY*NXY + ry0 + 1];
            vA[0] = Cl2m[0]*f0 + Cl2m[1]*f1 + Cl2m[2]*f2;
            vA[1] = Cl2m[3]*f0 + Cl2m[4]*f1 + Cl2m[5]*f2;
            vA[2] = Cl2m[6]*f0 + Cl2m[7]*f1 + Cl2m[8]*f2;
        }
        if (ry1 < NIN) {
            float f0 = kq[base + ry1 + 1];
            float f1 = kq[base + (size_t)NXY*NXY + ry1 + 1];
            float f2 = kq[base + 2*(size_t)NXY*NXY + ry1 + 1];
            vB[0] = Cl2m[0]*f0 + Cl2m[1]*f1 + Cl2m[2]*f2;
            vB[1] = Cl2m[3]*f0 + Cl2m[4]*f1 + Cl2m[5]*f2;
            vB[2] = Cl2m[6]*f0 + Cl2m[7]*f1 + Cl2m[8]*f2;
        }
    }
#pragma unroll
    for (int i = 0; i < 3; ++i) {
        size_t pb = (size_t)(e * NL3 + i) * 262144;
        size_t po = pb + (size_t)rx * 256 + p;
        size_t pe = po + 131072;
        unsigned short ha = f2bf(vA[i]);
        Gh[po] = ha; Gl[po] = f2bf(vA[i] - bf2f(ha));
        unsigned short hb = f2bf(vB[i]);
        Gh[pe] = hb; Gl[pe] = f2bf(vB[i] - bf2f(hb));
    }
}

// ---------------- parity-split bf16 MFMA GEMM: radix-2 DST step --------------------------------
#define EPLD 68
__global__ __launch_bounds__(256, 3) void gemm_dst(
    const unsigned short* __restrict__ Ah, const unsigned short* __restrict__ Al,
    const unsigned short* __restrict__ BoH, const unsigned short* __restrict__ BoL,
    const unsigned short* __restrict__ BeH, const unsigned short* __restrict__ BeL,
    unsigned short* __restrict__ Ch, unsigned short* __restrict__ Cl,
    float* __restrict__ Cf, const float* __restrict__ helm, float* __restrict__ part)
{
    __shared__ __attribute__((aligned(16))) char lds[49152];
    __shared__ float red[256];
    float* ep1 = (float*)lds;
    float* ep2 = ep1 + 32 * EPLD;
    const int id = blockIdx.x;
    const int nblk = id / 96, rr = id - nblk * 96;
    const int b = rr >> 3, mblk = rr & 7;
    const int m0 = mblk << 6;
    const int n0t = nblk << 5;
    const int t = threadIdx.x;
    const int w = t >> 6, lane = t & 63;
    const int wn = w >> 1, wm = w & 1;
    const int lr = lane & 15, g = lane >> 4;
    const unsigned short* AbH = Ah + (size_t)b * 262144;
    const unsigned short* AbL = Al + (size_t)b * 262144;

    const int srA = t >> 2;
    const int scA = ((t & 3) ^ ((srA >> 1) & 3)) * 8;
    const size_t gA = (size_t)(m0 + srA) * 256 + scA;
    const int dA = t * 16;
    const int hid = t & 127;
    const int srB = hid >> 2;
    const int scB = ((hid & 3) ^ ((srB >> 1) & 3)) * 8;
    const size_t gB = (size_t)(n0t + srB) * 256 + scB;
    const unsigned short* B1 = (t < 128) ? BoH : BoL;
    const unsigned short* B2 = (t < 128) ? BeH : BeL;
    const int dB1 = ((t < 128) ? 16384 : 18432) + hid * 16;
    const int dB2 = ((t < 128) ? 20480 : 22528) + hid * 16;

    auto STAGE = [&](int buf, int kt) {
        char* bb = lds + buf * 24576;
        int ke = kt * 32;
        GLDS(AbH + gA + ke,          bb + dA);
        GLDS(AbL + gA + ke,          bb + 4096  + dA);
        GLDS(AbH + 131072 + gA + ke, bb + 8192  + dA);
        GLDS(AbL + 131072 + gA + ke, bb + 12288 + dA);
        GLDS(B1 + gB + ke, bb + dB1);
        GLDS(B2 + gB + ke, bb + dB2);
    };

    f32x4 accO[2] = {}, accE[2] = {};
    int abyte[2];
#pragma unroll
    for (int i = 0; i < 2; ++i) {
        int ar = wm*32 + i*16 + lr;
        abyte[i] = ar*64 + ((g ^ ((ar >> 1) & 3)) * 16);
    }
    const int brl = wn*16 + lr;
    const int bby = brl*64 + ((g ^ ((brl >> 1) & 3)) * 16);

    STAGE(0, 0);
    __syncthreads();
    for (int it = 0; it < 8; ++it) {
        const int buf = it & 1;
        if (it < 7) STAGE(buf ^ 1, it + 1);
        const char* bb = lds + buf * 24576;
        bf16x8 boH = *(const bf16x8*)(bb + 16384 + bby);
        bf16x8 boL = *(const bf16x8*)(bb + 18432 + bby);
        bf16x8 beH = *(const bf16x8*)(bb + 20480 + bby);
        bf16x8 beL = *(const bf16x8*)(bb + 22528 + bby);
#pragma unroll
        for (int i = 0; i < 2; ++i) {
            bf16x8 aoH = *(const bf16x8*)(bb + abyte[i]);
            bf16x8 aoL = *(const bf16x8*)(bb + 4096  + abyte[i]);
            bf16x8 aeH = *(const bf16x8*)(bb + 8192  + abyte[i]);
            bf16x8 aeL = *(const bf16x8*)(bb + 12288 + abyte[i]);
            accO[i] = __builtin_amdgcn_mfma_f32_16x16x32_bf16(aoH, boH, accO[i], 0, 0, 0);
            accO[i] = __builtin_amdgcn_mfma_f32_16x16x32_bf16(aoH, boL, accO[i], 0, 0, 0);
            accO[i] = __builtin_amdgcn_mfma_f32_16x16x32_bf16(aoL, boH, accO[i], 0, 0, 0);
            accE[i] = __builtin_amdgcn_mfma_f32_16x16x32_bf16(aeH, beH, accE[i], 0, 0, 0);
            accE[i] = __builtin_amdgcn_mfma_f32_16x16x32_bf16(aeH, beL, accE[i], 0, 0, 0);
            accE[i] = __builtin_amdgcn_mfma_f32_16x16x32_bf16(aeL, beH, accE[i], 0, 0, 0);
        }
        __syncthreads();
    }

    const int mode = b % NL3;
    const float* hp = helm ? (helm + (size_t)mode * NIN * NIN) : nullptr;
    const int nl = wn*16 + lr;
    const int r1g = n0t + nl;
    const int r2g = 510 - n0t - nl;
#pragma unroll
    for (int i = 0; i < 2; ++i) {
        int ml = wm*32 + i*16 + 4*g;
#pragma unroll
        for (int r = 0; r < 4; ++r) {
            float o = accO[i][r], e = accE[i][r];
            float v1 = o + e, v2 = o - e;
            int mg = m0 + ml + r;
            if (hp && mg < NIN) {
                v1 /= hp[(size_t)r1g * NIN + mg];
                v2 /= hp[(size_t)r2g * NIN + mg];
            }
            ep1[nl*EPLD + ml + r] = v1;
            ep2[nl*EPLD + ml + r] = v2;
        }
    }
    __syncthreads();

    float lsum = 0.f;
    {
        const int row = t >> 3;
        const int cb = (t & 7) * 8;
        const int r1 = n0t + row;
        const int r2 = 510 - n0t - row;
        float v1[8], v2[8];
#pragma unroll
        for (int k = 0; k < 8; ++k) { v1[k] = ep1[row*EPLD + cb + k]; v2[k] = ep2[row*EPLD + cb + k]; }
        if (Cf) {
            size_t c1 = (size_t)b*262144 + (size_t)r1*512 + m0 + cb;
            size_t c2 = (size_t)b*262144 + (size_t)r2*512 + m0 + cb;
            f32x4 a0 = {v1[0], v1[1], v1[2], v1[3]};
            f32x4 a1 = {v1[4], v1[5], v1[6], v1[7]};
            f32x4 b0 = {v2[0], v2[1], v2[2], v2[3]};
            f32x4 b1 = {v2[4], v2[5], v2[6], v2[7]};
            *(f32x4*)(Cf + c1) = a0; *(f32x4*)(Cf + c1 + 4) = a1;
            *(f32x4*)(Cf + c2) = b0; *(f32x4*)(Cf + c2 + 4) = b1;
            if (nblk == 0 && t < 64) Cf[(size_t)b*262144 + (size_t)511*512 + m0 + t] = 0.f;
#pragma unroll
            for (int k = 0; k < 8; ++k) lsum += v1[k];
            if (r1 != 255) {
#pragma unroll
                for (int k = 0; k < 8; ++k) lsum += v2[k];
            }
        } else {
            auto STROW = [&](int rrow, const float* v) {
                size_t po = (size_t)b*262144 + (size_t)rrow*256 + ((m0 + cb) >> 1);
                size_t pe = po + 131072;
                unsigned short eh[4], el[4], oh[4], ol[4];
#pragma unroll
                for (int k = 0; k < 4; ++k) {
                    float ve = v[2*k], vo = v[2*k+1];
                    eh[k] = f2bf(ve); el[k] = f2bf(ve - bf2f(eh[k]));
                    oh[k] = f2bf(vo); ol[k] = f2bf(vo - bf2f(oh[k]));
                }
                *(uint2*)(Ch + po) = make_uint2((u32)eh[0] | ((u32)eh[1] << 16), (u32)eh[2] | ((u32)eh[3] << 16));
                *(uint2*)(Cl + po) = make_uint2((u32)el[0] | ((u32)el[1] << 16), (u32)el[2] | ((u32)el[3] << 16));
                *(uint2*)(Ch + pe) = make_uint2((u32)oh[0] | ((u32)oh[1] << 16), (u32)oh[2] | ((u32)oh[3] << 16));
                *(uint2*)(Cl + pe) = make_uint2((u32)ol[0] | ((u32)ol[1] << 16), (u32)ol[2] | ((u32)ol[3] << 16));
            };
            STROW(r1, v1);
            STROW(r2, v2);
            if (nblk == 0 && t < 32) {
                size_t z = (size_t)b*262144 + (size_t)511*256 + (m0 >> 1) + t;
                Ch[z] = 0; Cl[z] = 0; Ch[z + 131072] = 0; Cl[z + 131072] = 0;
            }
        }
    }

    if (part && Cf && mode < 2) {
        __syncthreads();
        red[t] = lsum;
        __syncthreads();
        for (int w2 = 128; w2 >= 1; w2 >>= 1) {
            if (t < w2) red[t] += red[t + w2];
            __syncthreads();
        }
        if (t == 0) {
            int plane8 = (b / NL3) * 2 + mode;
            part[plane8 * 64 + nblk * 8 + mblk] = red[0];
        }
    }
}

// ---------------- mega tail: dal + mode->layer + boundary dq + RK4 update (q and p) -------------
__global__ __launch_bounds__(256) void m2l_rk(
    float* __restrict__ ynext, float* __restrict__ ytmp,
    const float* __restrict__ ycur, const float* __restrict__ kq,
    const float* __restrict__ G, const float* __restrict__ hom,
    const float* __restrict__ Cm2l, const float* __restrict__ Amat,
    const float* __restrict__ alpha, const float* __restrict__ part,
    const float* __restrict__ tarr, int s, float c1, float c2, int accumulate)
{
    __shared__ float sp[128];
    __shared__ float sdal[2];
    const int yy = blockIdx.x * 64 + threadIdx.x;
    const int xx = blockIdx.y * 4 + threadIdx.y;
    const int e  = blockIdx.z;
    const int tt = threadIdx.y * 64 + threadIdx.x;

    if (tt < 128) sp[tt] = part[(e*2 + (tt >> 6))*64 + (tt & 63)];
    __syncthreads();
    if (tt == 0) {
        float s0 = 0.f, s1 = 0.f;
        for (int j = 0; j < 64; ++j) { s0 += sp[j]; s1 += sp[64 + j]; }
        const float inv = 1.0f / ((float)NXY * (float)NXY);
        float mm0 = s0 * inv, mm1 = s1 * inv;
        sdal[0] = alpha[0]*mm0 + alpha[1]*mm1;
        sdal[1] = alpha[2]*mm0 + alpha[3]*mm1;
    }
    __syncthreads();
    if (xx >= NXY || yy >= NXY) return;
    const float dal0 = sdal[0], dal1 = sdal[1];

    auto DP = [&](int px, int py, float* dp) {
        bool inter = (px >= 1 && px <= NIN && py >= 1 && py <= NIN);
        float mv0 = 0.f, mv1 = 0.f, mv2 = 0.f;
        if (inter) {
            size_t gb = (size_t)(e*NL3)*GLD*GLD + (size_t)(px-1)*GLD + (py-1);
            mv0 = G[gb]; mv1 = G[gb + (size_t)GLD*GLD]; mv2 = G[gb + 2*(size_t)GLD*GLD];
        }
        mv0 += dal0 * hom[(size_t)px*NXY + py];
        mv1 += dal1 * hom[(size_t)NXY*NXY + (size_t)px*NXY + py];
        dp[0] = Cm2l[0]*mv0 + Cm2l[1]*mv1 + Cm2l[2]*mv2;
        dp[1] = Cm2l[3]*mv0 + Cm2l[4]*mv1 + Cm2l[5]*mv2;
        dp[2] = Cm2l[6]*mv0 + Cm2l[7]*mv1 + Cm2l[8]*mv2;
    };

    float dp[3];
    DP(xx, yy, dp);

    const bool bnd = (xx == 0 || xx == NXY-1 || yy == 0 || yy == NXY-1);
    float kqv[3];
    if (!bnd) {
#pragma unroll
        for (int l = 0; l < 3; ++l)
            kqv[l] = kq[((size_t)(e*NL3 + l)*NXY + xx)*NXY + yy];
    } else {
        int xn, yn;
        if      (yy == 0)      { xn = xx;    yn = 1; }
        else if (yy == NXY-1)  { xn = xx;    yn = NXY-2; }
        else if (xx == 0)      { xn = 1;     yn = yy; }
        else                   { xn = NXY-2; yn = yy; }
        float dpn[3];
        DP(xn, yn, dpn);
#pragma unroll
        for (int l = 0; l < 3; ++l) {
            float lpb = ZFBCf * INVF0DX2f * (dpn[l] - dp[l]);
            kqv[l] = lpb - (Amat[l*3+0]*dp[0] + Amat[l*3+1]*dp[1] + Amat[l*3+2]*dp[2]);
        }
    }

    const float dt = tarr[s+1] - tarr[s];
    const float a1 = c1 * dt, a2 = c2 * dt;
#pragma unroll
    for (int l = 0; l < 3; ++l) {
        size_t oq = ((size_t)(e*NL3 + l)*NXY + xx)*NXY + yy;
        size_t op = oq + FS;
        float xq = ycur[oq], xp = ycur[op];
        float bq = accumulate ? ynext[oq] : xq;
        float bp = accumulate ? ynext[op] : xp;
        ynext[oq] = bq + a1 * kqv[l];
        ynext[op] = bp + a1 * dp[l];
        if (ytmp) {
            ytmp[oq] = xq + a2 * kqv[l];
            ytmp[op] = xp + a2 * dp[l];
        }
    }
}

__global__ void copy_kernel(float4* __restrict__ out, const float4* __restrict__ in, long n4) {
    for (long i = (long)blockIdx.x * blockDim.x + threadIdx.x; i < n4;
         i += (long)gridDim.x * blockDim.x)
        out[i] = in[i];
}

// ===============================================================================================
extern "C" void kernel_launch(void* const* d_in, const int* in_sizes, int n_in,
                              void* d_out, int out_size, void* d_ws, size_t ws_size,
                              hipStream_t stream) {
    const float* y0    = (const float*)d_in[0];
    const float* tarr  = (const float*)d_in[1];
    const float* Amat  = (const float*)d_in[2];
    const float* Cl2m  = (const float*)d_in[3];
    const float* Cm2l  = (const float*)d_in[4];
    const float* helm  = (const float*)d_in[5];
    const float* alpha = (const float*)d_in[6];
    const float* hom   = (const float*)d_in[7];
    const float* wind  = (const float*)d_in[8];
    float* out = (float*)d_out;
    char* base = (char*)d_ws;

    unsigned short* BoH = (unsigned short*)base;
    unsigned short* BoL = BoH + 65536;
    unsigned short* BeH = BoL + 65536;
    unsigned short* BeL = BeH + 65536;
    float* ytmp = (float*)(base + 1024*1024);
    float* kq   = ytmp + 2*FS;
    char*  REGb = (char*)(kq + FS);
    unsigned short* P0h = (unsigned short*)REGb;
    unsigned short* P0l = P0h + GSZ;
    unsigned short* P1h = P0l + GSZ;
    unsigned short* P1l = P1h + GSZ;
    float* R4 = (float*)REGb;
    float* partial = (float*)(REGb + (size_t)2*FS*sizeof(float));

    const dim3 bSt(64, 4, 1);
    const dim3 gM(9, 129, NE4);
    const dim3 gL2M(4, 128, NE4);
    const dim3 gF(8, 32, NB);
    const dim3 gG(768, 1, 1);
    const long n4 = 2*FS/4;

    initB_kernel<<<256, 256, 0, stream>>>(BoH, BoL, BeH, BeL);
    copy_kernel<<<1024, 256, 0, stream>>>((float4*)out, (const float4*)y0, n4);

    auto evalstep = [&](const float* y, const float* ycur, float* ynext, float* otmp,
                        int s, float c1, float c2, int accumulate) {
        fused_rhs<<<gF, 256, 0, stream>>>(kq, y, y + FS, wind);
        l2m_kernel<<<gL2M, bSt, 0, stream>>>(P0h, P0l, kq, Cl2m);
        gemm_dst<<<gG, 256, 0, stream>>>(P0h, P0l, BoH, BoL, BeH, BeL, P1h, P1l, nullptr, nullptr, nullptr);
        gemm_dst<<<gG, 256, 0, stream>>>(P1h, P1l, BoH, BoL, BeH, BeL, P0h, P0l, nullptr, helm, nullptr);
        gemm_dst<<<gG, 256, 0, stream>>>(P0h, P0l, BoH, BoL, BeH, BeL, P1h, P1l, nullptr, nullptr, nullptr);
        gemm_dst<<<gG, 256, 0, stream>>>(P1h, P1l, BoH, BoL, BeH, BeL, nullptr, nullptr, R4, nullptr, partial);
        m2l_rk<<<gM, bSt, 0, stream>>>(ynext, otmp, ycur, kq, R4, hom, Cm2l, Amat,
                                       alpha, partial, tarr, s, c1, c2, accumulate);
    };

    for (int s = 0; s < NSTEPS; ++s) {
        float* ycur  = out + (size_t)s * 2 * FS;
        float* ynext = out + (size_t)(s + 1) * 2 * FS;
        evalstep(ycur, ycur, ynext, ytmp, s, 1.f/6.f, 0.5f, 0);
        evalstep(ytmp, ycur, ynext, ytmp, s, 2.f/6.f, 0.5f, 1);
        evalstep(ytmp, ycur, ynext, ytmp, s, 2.f/6.f, 1.0f, 1);
        evalstep(ytmp, ycur, ynext, nullptr, s, 1.f/6.f, 0.f, 1);
    }
}

// Round 15
// 2003.832 us; speedup vs baseline: 1.1263x; 1.1263x over previous
//
#include <hip/hip_runtime.h>
#include <math.h>

#define NXY 513
#define NIN 511
#define NL3 3
#define NE4 4
#define NB 12
#define GLD 512

static constexpr long FS  = (long)NE4 * NL3 * NXY * NXY;   // 3,158,028 floats
static constexpr long GSZ = (long)NB * GLD * GLD;          // 3,145,728 elements
static constexpr int  NSTEPS = 4;

static constexpr double dF0 = 9.375e-05;
static constexpr double dDX = 10000.0;
static constexpr float ZFBCf     = (float)(0.2 / (1.0 + 0.5 * 0.2));
static constexpr float JACCf     = (float)(1.0 / (dF0 * dDX * dDX));
static constexpr float HYPCf     = (float)(2.0e9 / (dF0 * dF0) / (dDX*dDX*dDX*dDX*dDX*dDX));
static constexpr float BFCf      = (float)(2.0 / (2.0 * dF0 * dDX * dDX * (-2900.0)));
static constexpr float INVF0DX2f = (float)(1.0 / ((dF0 * dDX) * (dF0 * dDX)));

typedef short  bf16x8 __attribute__((ext_vector_type(8)));
typedef float  f32x4  __attribute__((ext_vector_type(4)));
typedef unsigned int u32;
typedef __attribute__((address_space(1))) const u32 GAS;
typedef __attribute__((address_space(3))) u32 LAS;
#define GLDS(gp, lp) __builtin_amdgcn_global_load_lds((GAS*)(gp), (LAS*)(lp), 16, 0, 0)

__device__ __forceinline__ unsigned short f2bf(float x) {
    unsigned int u = __float_as_uint(x);
    return (unsigned short)((u + 0x7FFFu + ((u >> 16) & 1u)) >> 16);
}
__device__ __forceinline__ float bf2f(unsigned short h) {
    return __uint_as_float(((unsigned int)h) << 16);
}

// ---------------- parity-split DST matrices (bf16 hi/lo), 256x256 each --------------------------
__global__ void initB_kernel(unsigned short* __restrict__ BoH, unsigned short* __restrict__ BoL,
                             unsigned short* __restrict__ BeH, unsigned short* __restrict__ BeL) {
    int j = threadIdx.x;
    int n = blockIdx.x;
    int idx = n * 256 + j;
    int mo = ((n + 1) * (2 * j + 1)) & 1023;
    int me = ((n + 1) * (2 * j + 2)) & 1023;
    float fo = (float)(0.0625 * sin(M_PI * (double)mo / 512.0));
    float fe = (float)(0.0625 * sin(M_PI * (double)me / 512.0));
    unsigned short oh = f2bf(fo);
    BoH[idx] = oh; BoL[idx] = f2bf(fo - bf2f(oh));
    unsigned short eh = f2bf(fe);
    BeH[idx] = eh; BeL[idx] = f2bf(fe - bf2f(eh));
}

// ---------------- fused lap(lap_bc(lap_bc(p))) + jacobian + wind + friction (12 planes) ---------
__global__ __launch_bounds__(256) void fused_rhs(
    float* __restrict__ kq, const float* __restrict__ q, const float* __restrict__ p,
    const float* __restrict__ wind)
{
    __shared__ float ps[22][72];
    __shared__ float qs[22][72];
    __shared__ float l1[22][72];
    __shared__ float l2[22][72];
    const int c  = blockIdx.z;
    const int x0 = 1 + blockIdx.y * 16;
    const int y0 = 1 + blockIdx.x * 64;
    const int t  = threadIdx.x;
    const size_t off = (size_t)c * NXY * NXY;
    const float* pp = p + off;
    const float* qp = q + off;

    for (int idx = t; idx < 22 * 70; idx += 256) {
        int i = idx / 70, j = idx % 70;
        int gx = x0 - 3 + i, gy = y0 - 3 + j;
        bool in = (gx >= 0 && gx < NXY && gy >= 0 && gy < NXY);
        size_t go = (size_t)gx * NXY + gy;
        ps[i][j] = in ? pp[go] : 0.f;
        qs[i][j] = in ? qp[go] : 0.f;
    }
    __syncthreads();

#define LAPBC(a, i, j, gx, gy) \
    ((gy) == 0       ? ZFBCf * (a[i][(j)+1] - a[i][j]) : \
     (gy) == NXY-1   ? ZFBCf * (a[i][(j)-1] - a[i][j]) : \
     (gx) == 0       ? ZFBCf * (a[(i)+1][j] - a[i][j]) : \
     (gx) == NXY-1   ? ZFBCf * (a[(i)-1][j] - a[i][j]) : \
     a[(i)+1][j] + a[(i)-1][j] + a[i][(j)+1] + a[i][(j)-1] - 4.f * a[i][j])

    for (int idx = t; idx < 20 * 68; idx += 256) {
        int i = 1 + idx / 68, j = 1 + idx % 68;
        int gx = x0 - 3 + i, gy = y0 - 3 + j;
        float v = 0.f;
        if (gx >= 0 && gx < NXY && gy >= 0 && gy < NXY) v = LAPBC(ps, i, j, gx, gy);
        l1[i][j] = v;
    }
    __syncthreads();

    for (int idx = t; idx < 18 * 66; idx += 256) {
        int i = 2 + idx / 66, j = 2 + idx % 66;
        int gx = x0 - 3 + i, gy = y0 - 3 + j;
        float v = 0.f;
        if (gx >= 0 && gx < NXY && gy >= 0 && gy < NXY) v = LAPBC(l1, i, j, gx, gy);
        l2[i][j] = v;
    }
    __syncthreads();
#undef LAPBC

    const int l = c % NL3;
    for (int idx = t; idx < 16 * 64; idx += 256) {
        int i = 3 + idx / 64, j = 3 + idx % 64;
        int gx = x0 - 3 + i, gy = y0 - 3 + j;
        if (gx > NIN || gy > NIN) continue;
        float fmm=qs[i-1][j-1], fm0=qs[i-1][j], fmp=qs[i-1][j+1];
        float f0m=qs[i][j-1],                    f0p=qs[i][j+1];
        float fpm=qs[i+1][j-1], fp0=qs[i+1][j], fpp=qs[i+1][j+1];
        float gmm=ps[i-1][j-1], gm0=ps[i-1][j], gmp=ps[i-1][j+1];
        float g0m=ps[i][j-1],   g00=ps[i][j],   g0p=ps[i][j+1];
        float gpm=ps[i+1][j-1], gp0=ps[i+1][j], gpp=ps[i+1][j+1];
        float J1 = (fp0 - fm0) * (g0p - g0m) - (gp0 - gm0) * (f0p - f0m);
        float J2 = fp0 * (gpp - gpm) - fm0 * (gmp - gmm);
        float J3 = f0p * (gpp - gmp) - f0m * (gpm - gmm);
        float J4 = g0p * (fpp - fmp) - g0m * (fpm - fmm);
        float J5 = gp0 * (fpp - fpm) - gm0 * (fmp - fmm);
        float jac = (J1 + J2 - J3 + J4 - J5) * (1.0f / 12.0f);
        float lap3 = l2[i+1][j] + l2[i-1][j] + l2[i][j+1] + l2[i][j-1] - 4.f * l2[i][j];
        float v = JACCf * jac - HYPCf * lap3;
        if (l == 0)       v += wind[(size_t)(gx-1) * NIN + (gy-1)];
        if (l == NL3-1)   v += BFCf * (gp0 + gm0 + g0p + g0m - 4.f * g00);
        kq[off + (size_t)gx * NXY + gy] = v;
    }
}

// ---------------- layer->mode, writes bf16 hi/lo in PARITY-SPLIT layout ------------------------
__global__ void l2m_kernel(unsigned short* __restrict__ Gh, unsigned short* __restrict__ Gl,
                           const float* __restrict__ kq, const float* __restrict__ Cl2m) {
    int p  = blockIdx.x * blockDim.x + threadIdx.x;   // pair index 0..255
    int rx = blockIdx.y * blockDim.y + threadIdx.y;   // 0..511
    int e = blockIdx.z;
    int ry0 = 2 * p, ry1 = 2 * p + 1;
    float vA[3] = {0.f, 0.f, 0.f}, vB[3] = {0.f, 0.f, 0.f};
    if (rx < NIN) {
        size_t base = ((size_t)(e * NL3) * NXY + (rx + 1)) * NXY;
        if (ry0 < NIN) {
            float f0 = kq[base + ry0 + 1];
            float f1 = kq[base + (size_t)NXY*NXY + ry0 + 1];
            float f2 = kq[base + 2*(size_t)NXY*NXY + ry0 + 1];
            vA[0] = Cl2m[0]*f0 + Cl2m[1]*f1 + Cl2m[2]*f2;
            vA[1] = Cl2m[3]*f0 + Cl2m[4]*f1 + Cl2m[5]*f2;
            vA[2] = Cl2m[6]*f0 + Cl2m[7]*f1 + Cl2m[8]*f2;
        }
        if (ry1 < NIN) {
            float f0 = kq[base + ry1 + 1];
            float f1 = kq[base + (size_t)NXY*NXY + ry1 + 1];
            float f2 = kq[base + 2*(size_t)NXY*NXY + ry1 + 1];
            vB[0] = Cl2m[0]*f0 + Cl2m[1]*f1 + Cl2m[2]*f2;
            vB[1] = Cl2m[3]*f0 + Cl2m[4]*f1 + Cl2m[5]*f2;
            vB[2] = Cl2m[6]*f0 + Cl2m[7]*f1 + Cl2m[8]*f2;
        }
    }
#pragma unroll
    for (int i = 0; i < 3; ++i) {
        size_t pb = (size_t)(e * NL3 + i) * 262144;
        size_t po = pb + (size_t)rx * 256 + p;
        size_t pe = po + 131072;
        unsigned short ha = f2bf(vA[i]);
        Gh[po] = ha; Gl[po] = f2bf(vA[i] - bf2f(ha));
        unsigned short hb = f2bf(vB[i]);
        Gh[pe] = hb; Gl[pe] = f2bf(vB[i] - bf2f(hb));
    }
}

// ---------------- parity-split bf16 MFMA GEMM: radix-2 DST step --------------------------------
#define EPLD 68
__global__ __launch_bounds__(256, 3) void gemm_dst(
    const unsigned short* __restrict__ Ah, const unsigned short* __restrict__ Al,
    const unsigned short* __restrict__ BoH, const unsigned short* __restrict__ BoL,
    const unsigned short* __restrict__ BeH, const unsigned short* __restrict__ BeL,
    unsigned short* __restrict__ Ch, unsigned short* __restrict__ Cl,
    float* __restrict__ Cf, const float* __restrict__ helm, float* __restrict__ part)
{
    __shared__ __attribute__((aligned(16))) char lds[49152];
    __shared__ float red[256];
    float* ep1 = (float*)lds;
    float* ep2 = ep1 + 32 * EPLD;
    const int id = blockIdx.x;
    const int nblk = id / 96, rr = id - nblk * 96;
    const int b = rr >> 3, mblk = rr & 7;
    const int m0 = mblk << 6;
    const int n0t = nblk << 5;
    const int t = threadIdx.x;
    const int w = t >> 6, lane = t & 63;
    const int wn = w >> 1, wm = w & 1;
    const int lr = lane & 15, g = lane >> 4;
    const unsigned short* AbH = Ah + (size_t)b * 262144;
    const unsigned short* AbL = Al + (size_t)b * 262144;

    const int srA = t >> 2;
    const int scA = ((t & 3) ^ ((srA >> 1) & 3)) * 8;
    const size_t gA = (size_t)(m0 + srA) * 256 + scA;
    const int dA = t * 16;
    const int hid = t & 127;
    const int srB = hid >> 2;
    const int scB = ((hid & 3) ^ ((srB >> 1) & 3)) * 8;
    const size_t gB = (size_t)(n0t + srB) * 256 + scB;
    const unsigned short* B1 = (t < 128) ? BoH : BoL;
    const unsigned short* B2 = (t < 128) ? BeH : BeL;
    const int dB1 = ((t < 128) ? 16384 : 18432) + hid * 16;
    const int dB2 = ((t < 128) ? 20480 : 22528) + hid * 16;

    auto STAGE = [&](int buf, int kt) {
        char* bb = lds + buf * 24576;
        int ke = kt * 32;
        GLDS(AbH + gA + ke,          bb + dA);
        GLDS(AbL + gA + ke,          bb + 4096  + dA);
        GLDS(AbH + 131072 + gA + ke, bb + 8192  + dA);
        GLDS(AbL + 131072 + gA + ke, bb + 12288 + dA);
        GLDS(B1 + gB + ke, bb + dB1);
        GLDS(B2 + gB + ke, bb + dB2);
    };

    f32x4 accO[2] = {}, accE[2] = {};
    int abyte[2];
#pragma unroll
    for (int i = 0; i < 2; ++i) {
        int ar = wm*32 + i*16 + lr;
        abyte[i] = ar*64 + ((g ^ ((ar >> 1) & 3)) * 16);
    }
    const int brl = wn*16 + lr;
    const int bby = brl*64 + ((g ^ ((brl >> 1) & 3)) * 16);

    STAGE(0, 0);
    __syncthreads();
    for (int it = 0; it < 8; ++it) {
        const int buf = it & 1;
        if (it < 7) STAGE(buf ^ 1, it + 1);
        const char* bb = lds + buf * 24576;
        bf16x8 boH = *(const bf16x8*)(bb + 16384 + bby);
        bf16x8 boL = *(const bf16x8*)(bb + 18432 + bby);
        bf16x8 beH = *(const bf16x8*)(bb + 20480 + bby);
        bf16x8 beL = *(const bf16x8*)(bb + 22528 + bby);
#pragma unroll
        for (int i = 0; i < 2; ++i) {
            bf16x8 aoH = *(const bf16x8*)(bb + abyte[i]);
            bf16x8 aoL = *(const bf16x8*)(bb + 4096  + abyte[i]);
            bf16x8 aeH = *(const bf16x8*)(bb + 8192  + abyte[i]);
            bf16x8 aeL = *(const bf16x8*)(bb + 12288 + abyte[i]);
            accO[i] = __builtin_amdgcn_mfma_f32_16x16x32_bf16(aoH, boH, accO[i], 0, 0, 0);
            accO[i] = __builtin_amdgcn_mfma_f32_16x16x32_bf16(aoH, boL, accO[i], 0, 0, 0);
            accO[i] = __builtin_amdgcn_mfma_f32_16x16x32_bf16(aoL, boH, accO[i], 0, 0, 0);
            accE[i] = __builtin_amdgcn_mfma_f32_16x16x32_bf16(aeH, beH, accE[i], 0, 0, 0);
            accE[i] = __builtin_amdgcn_mfma_f32_16x16x32_bf16(aeH, beL, accE[i], 0, 0, 0);
            accE[i] = __builtin_amdgcn_mfma_f32_16x16x32_bf16(aeL, beH, accE[i], 0, 0, 0);
        }
        __syncthreads();
    }

    const int mode = b % NL3;
    const float* hp = helm ? (helm + (size_t)mode * NIN * NIN) : nullptr;
    const int nl = wn*16 + lr;
    const int r1g = n0t + nl;
    const int r2g = 510 - n0t - nl;
#pragma unroll
    for (int i = 0; i < 2; ++i) {
        int ml = wm*32 + i*16 + 4*g;
#pragma unroll
        for (int r = 0; r < 4; ++r) {
            float o = accO[i][r], e = accE[i][r];
            float v1 = o + e, v2 = o - e;
            int mg = m0 + ml + r;
            if (hp && mg < NIN) {
                v1 /= hp[(size_t)r1g * NIN + mg];
                v2 /= hp[(size_t)r2g * NIN + mg];
            }
            ep1[nl*EPLD + ml + r] = v1;
            ep2[nl*EPLD + ml + r] = v2;
        }
    }
    __syncthreads();

    float lsum = 0.f;
    {
        const int row = t >> 3;
        const int cb = (t & 7) * 8;
        const int r1 = n0t + row;
        const int r2 = 510 - n0t - row;
        float v1[8], v2[8];
#pragma unroll
        for (int k = 0; k < 8; ++k) { v1[k] = ep1[row*EPLD + cb + k]; v2[k] = ep2[row*EPLD + cb + k]; }
        if (Cf) {
            size_t c1 = (size_t)b*262144 + (size_t)r1*512 + m0 + cb;
            size_t c2 = (size_t)b*262144 + (size_t)r2*512 + m0 + cb;
            f32x4 a0 = {v1[0], v1[1], v1[2], v1[3]};
            f32x4 a1 = {v1[4], v1[5], v1[6], v1[7]};
            f32x4 b0 = {v2[0], v2[1], v2[2], v2[3]};
            f32x4 b1 = {v2[4], v2[5], v2[6], v2[7]};
            *(f32x4*)(Cf + c1) = a0; *(f32x4*)(Cf + c1 + 4) = a1;
            *(f32x4*)(Cf + c2) = b0; *(f32x4*)(Cf + c2 + 4) = b1;
            if (nblk == 0 && t < 64) Cf[(size_t)b*262144 + (size_t)511*512 + m0 + t] = 0.f;
#pragma unroll
            for (int k = 0; k < 8; ++k) lsum += v1[k];
            if (r1 != 255) {
#pragma unroll
                for (int k = 0; k < 8; ++k) lsum += v2[k];
            }
        } else {
            auto STROW = [&](int rrow, const float* v) {
                size_t po = (size_t)b*262144 + (size_t)rrow*256 + ((m0 + cb) >> 1);
                size_t pe = po + 131072;
                unsigned short eh[4], el[4], oh[4], ol[4];
#pragma unroll
                for (int k = 0; k < 4; ++k) {
                    float ve = v[2*k], vo = v[2*k+1];
                    eh[k] = f2bf(ve); el[k] = f2bf(ve - bf2f(eh[k]));
                    oh[k] = f2bf(vo); ol[k] = f2bf(vo - bf2f(oh[k]));
                }
                *(uint2*)(Ch + po) = make_uint2((u32)eh[0] | ((u32)eh[1] << 16), (u32)eh[2] | ((u32)eh[3] << 16));
                *(uint2*)(Cl + po) = make_uint2((u32)el[0] | ((u32)el[1] << 16), (u32)el[2] | ((u32)el[3] << 16));
                *(uint2*)(Ch + pe) = make_uint2((u32)oh[0] | ((u32)oh[1] << 16), (u32)oh[2] | ((u32)oh[3] << 16));
                *(uint2*)(Cl + pe) = make_uint2((u32)ol[0] | ((u32)ol[1] << 16), (u32)ol[2] | ((u32)ol[3] << 16));
            };
            STROW(r1, v1);
            STROW(r2, v2);
            if (nblk == 0 && t < 32) {
                size_t z = (size_t)b*262144 + (size_t)511*256 + (m0 >> 1) + t;
                Ch[z] = 0; Cl[z] = 0; Ch[z + 131072] = 0; Cl[z + 131072] = 0;
            }
        }
    }

    if (part && Cf && mode < 2) {
        __syncthreads();
        red[t] = lsum;
        __syncthreads();
        for (int w2 = 128; w2 >= 1; w2 >>= 1) {
            if (t < w2) red[t] += red[t + w2];
            __syncthreads();
        }
        if (t == 0) {
            int plane8 = (b / NL3) * 2 + mode;
            part[plane8 * 64 + nblk * 8 + mblk] = red[0];
        }
    }
}

// ---------------- m2l + dalpha + boundary dq (kp written everywhere; kq boundary overwritten) ---
__global__ __launch_bounds__(256) void m2l_bound(
    float* __restrict__ kp, float* __restrict__ kq,
    const float* __restrict__ G, const float* __restrict__ hom,
    const float* __restrict__ Cm2l, const float* __restrict__ Amat,
    const float* __restrict__ alpha, const float* __restrict__ part)
{
    __shared__ float sp[128];
    __shared__ float sdal[2];
    const int yy = blockIdx.x * 64 + threadIdx.x;
    const int xx = blockIdx.y * 4 + threadIdx.y;
    const int e  = blockIdx.z;
    const int tt = threadIdx.y * 64 + threadIdx.x;

    if (tt < 128) sp[tt] = part[(e*2 + (tt >> 6))*64 + (tt & 63)];
    __syncthreads();
    if (tt == 0) {
        float s0 = 0.f, s1 = 0.f;
        for (int j = 0; j < 64; ++j) { s0 += sp[j]; s1 += sp[64 + j]; }
        const float inv = 1.0f / ((float)NXY * (float)NXY);
        float mm0 = s0 * inv, mm1 = s1 * inv;
        sdal[0] = alpha[0]*mm0 + alpha[1]*mm1;
        sdal[1] = alpha[2]*mm0 + alpha[3]*mm1;
    }
    __syncthreads();
    if (xx >= NXY || yy >= NXY) return;
    const float dal0 = sdal[0], dal1 = sdal[1];

    auto DP = [&](int px, int py, float* dp) {
        bool inter = (px >= 1 && px <= NIN && py >= 1 && py <= NIN);
        float mv0 = 0.f, mv1 = 0.f, mv2 = 0.f;
        if (inter) {
            size_t gb = (size_t)(e*NL3)*GLD*GLD + (size_t)(px-1)*GLD + (py-1);
            mv0 = G[gb]; mv1 = G[gb + (size_t)GLD*GLD]; mv2 = G[gb + 2*(size_t)GLD*GLD];
        }
        mv0 += dal0 * hom[(size_t)px*NXY + py];
        mv1 += dal1 * hom[(size_t)NXY*NXY + (size_t)px*NXY + py];
        dp[0] = Cm2l[0]*mv0 + Cm2l[1]*mv1 + Cm2l[2]*mv2;
        dp[1] = Cm2l[3]*mv0 + Cm2l[4]*mv1 + Cm2l[5]*mv2;
        dp[2] = Cm2l[6]*mv0 + Cm2l[7]*mv1 + Cm2l[8]*mv2;
    };

    float dp[3];
    DP(xx, yy, dp);
#pragma unroll
    for (int l = 0; l < 3; ++l)
        kp[((size_t)(e*NL3 + l)*NXY + xx)*NXY + yy] = dp[l];

    const bool bnd = (xx == 0 || xx == NXY-1 || yy == 0 || yy == NXY-1);
    if (bnd) {
        int xn, yn;
        if      (yy == 0)      { xn = xx;    yn = 1; }
        else if (yy == NXY-1)  { xn = xx;    yn = NXY-2; }
        else if (xx == 0)      { xn = 1;     yn = yy; }
        else                   { xn = NXY-2; yn = yy; }
        float dpn[3];
        DP(xn, yn, dpn);
#pragma unroll
        for (int l = 0; l < 3; ++l) {
            float lpb = ZFBCf * INVF0DX2f * (dpn[l] - dp[l]);
            kq[((size_t)(e*NL3 + l)*NXY + xx)*NXY + yy] =
                lpb - (Amat[l*3+0]*dp[0] + Amat[l*3+1]*dp[1] + Amat[l*3+2]*dp[2]);
        }
    }
}

// ---------------- fused RK4 update ---------------------------------------------------------------
__global__ void rk_fused(float4* __restrict__ o1, float4* __restrict__ o2,
                         const float4* __restrict__ x, const float4* __restrict__ k,
                         float c1, float c2, int accumulate,
                         const float* __restrict__ t, int s, long n4) {
    float dt = t[s+1] - t[s];
    float a1 = c1 * dt, a2 = c2 * dt;
    for (long i = (long)blockIdx.x * blockDim.x + threadIdx.x; i < n4;
         i += (long)gridDim.x * blockDim.x) {
        float4 kk = k[i], xx = x[i];
        float4 b0 = accumulate ? o1[i] : xx;
        o1[i] = make_float4(b0.x + a1*kk.x, b0.y + a1*kk.y, b0.z + a1*kk.z, b0.w + a1*kk.w);
        if (o2) o2[i] = make_float4(xx.x + a2*kk.x, xx.y + a2*kk.y, xx.z + a2*kk.z, xx.w + a2*kk.w);
    }
}

__global__ void copy_kernel(float4* __restrict__ out, const float4* __restrict__ in, long n4) {
    for (long i = (long)blockIdx.x * blockDim.x + threadIdx.x; i < n4;
         i += (long)gridDim.x * blockDim.x)
        out[i] = in[i];
}

// ===============================================================================================
extern "C" void kernel_launch(void* const* d_in, const int* in_sizes, int n_in,
                              void* d_out, int out_size, void* d_ws, size_t ws_size,
                              hipStream_t stream) {
    const float* y0    = (const float*)d_in[0];
    const float* tarr  = (const float*)d_in[1];
    const float* Amat  = (const float*)d_in[2];
    const float* Cl2m  = (const float*)d_in[3];
    const float* Cm2l  = (const float*)d_in[4];
    const float* helm  = (const float*)d_in[5];
    const float* alpha = (const float*)d_in[6];
    const float* hom   = (const float*)d_in[7];
    const float* wind  = (const float*)d_in[8];
    float* out = (float*)d_out;
    char* base = (char*)d_ws;

    unsigned short* BoH = (unsigned short*)base;
    unsigned short* BoL = BoH + 65536;
    unsigned short* BeH = BoL + 65536;
    unsigned short* BeL = BeH + 65536;
    float* ytmp = (float*)(base + 1024*1024);
    float* kbuf = ytmp + 2*FS;
    char*  REGb = (char*)(kbuf + 2*FS);
    unsigned short* P0h = (unsigned short*)REGb;
    unsigned short* P0l = P0h + GSZ;
    unsigned short* P1h = P0l + GSZ;
    unsigned short* P1l = P1h + GSZ;
    float* R4 = (float*)REGb;
    float* partial = (float*)(REGb + (size_t)2*FS*sizeof(float));

    const dim3 bSt(64, 4, 1);
    const dim3 gSt4((NXY + 63)/64, (NXY + 3)/4, NE4);
    const dim3 gL2M(4, 128, NE4);
    const dim3 gF(8, 32, NB);
    const dim3 gG(768, 1, 1);
    const long n4 = 2*FS/4;

    initB_kernel<<<256, 256, 0, stream>>>(BoH, BoL, BeH, BeL);
    copy_kernel<<<1024, 256, 0, stream>>>((float4*)out, (const float4*)y0, n4);

    auto deriv = [&](const float* y, float* k) {
        const float* q = y;  const float* p = y + FS;
        float* kq = k;       float* kp = k + FS;
        fused_rhs<<<gF, 256, 0, stream>>>(kq, q, p, wind);
        l2m_kernel<<<gL2M, bSt, 0, stream>>>(P0h, P0l, kq, Cl2m);
        gemm_dst<<<gG, 256, 0, stream>>>(P0h, P0l, BoH, BoL, BeH, BeL, P1h, P1l, nullptr, nullptr, nullptr);
        gemm_dst<<<gG, 256, 0, stream>>>(P1h, P1l, BoH, BoL, BeH, BeL, P0h, P0l, nullptr, helm, nullptr);
        gemm_dst<<<gG, 256, 0, stream>>>(P0h, P0l, BoH, BoL, BeH, BeL, P1h, P1l, nullptr, nullptr, nullptr);
        gemm_dst<<<gG, 256, 0, stream>>>(P1h, P1l, BoH, BoL, BeH, BeL, nullptr, nullptr, R4, nullptr, partial);
        m2l_bound<<<gSt4, bSt, 0, stream>>>(kp, kq, R4, hom, Cm2l, Amat, alpha, partial);
    };

    for (int s = 0; s < NSTEPS; ++s) {
        float* ycur  = out + (size_t)s * 2 * FS;
        float* ynext = out + (size_t)(s + 1) * 2 * FS;
        deriv(ycur, kbuf);
        rk_fused<<<1024, 256, 0, stream>>>((float4*)ynext, (float4*)ytmp, (const float4*)ycur,
                                           (const float4*)kbuf, 1.f/6.f, 0.5f, 0, tarr, s, n4);
        deriv(ytmp, kbuf);
        rk_fused<<<1024, 256, 0, stream>>>((float4*)ynext, (float4*)ytmp, (const float4*)ycur,
                                           (const float4*)kbuf, 2.f/6.f, 0.5f, 1, tarr, s, n4);
        deriv(ytmp, kbuf);
        rk_fused<<<1024, 256, 0, stream>>>((float4*)ynext, (float4*)ytmp, (const float4*)ycur,
                                           (const float4*)kbuf, 2.f/6.f, 1.0f, 1, tarr, s, n4);
        deriv(ytmp, kbuf);
        rk_fused<<<1024, 256, 0, stream>>>((float4*)ynext, nullptr, (const float4*)ycur,
                                           (const float4*)kbuf, 1.f/6.f, 0.f, 1, tarr, s, n4);
    }
}